// Round 1
// baseline (4239.274 us; speedup 1.0000x reference)
//
#include <hip/hip_runtime.h>
#include <cstdint>

// ---------------- problem constants ----------------
#define NB 64        // batch
#define TT 8         // timesteps
#define NN 2000      // nodes
#define NF 16        // in features
#define NCH 64       // channels
#define NPAD 2048    // padded node dim
#define BCD 4096     // NB*NCH
#define ITEMS 128000 // NB*NN

// ws offsets (floats)
#define OFF_ADP   0                        // 2048*2048   = 4194304
#define OFF_S     4194304                  // 2048*4096   = 8388608
#define OFF_X1    (OFF_S + 8388608)
#define OFF_X2    (OFF_X1 + 8388608)
#define OFF_C01   (OFF_X2 + 8388608)       // 128
#define OFF_WGCNT (OFF_C01 + 128)          // 192*64 = 12288 (gcn_w transposed)
#define OFF_W1TT  (OFF_WGCNT + 12288)      // 2*64*64 = 8192 (head w1 gx-part transposed)
#define OFF_PART  (OFF_W1TT + 8192)        // 2048*132 partials

// ---------------- K0: tiny precompute (transposes + task-dot) ----------------
__global__ void prep_kernel(const float* __restrict__ gcn_w,
                            const float* __restrict__ h0_w1, const float* __restrict__ h0_b1,
                            const float* __restrict__ h1_w1, const float* __restrict__ h1_b1,
                            const float* __restrict__ task_emb,
                            float* __restrict__ c01, float* __restrict__ wgcnT,
                            float* __restrict__ w1tT)
{
    int tid = threadIdx.x;
    for (int idx = tid; idx < 64 * 192; idx += 256) {
        int o = idx / 192, j = idx % 192;
        wgcnT[j * 64 + o] = gcn_w[idx];
    }
    for (int idx = tid; idx < 4096; idx += 256) {
        int o = idx >> 6, c = idx & 63;
        w1tT[c * 64 + o]        = h0_w1[o * 128 + 64 + c];
        w1tT[4096 + c * 64 + o] = h1_w1[o * 128 + 64 + c];
    }
    if (tid < 128) {
        int head = tid >> 6, o = tid & 63;
        const float* w1 = head ? h1_w1 : h0_w1;
        const float* b1 = head ? h1_b1 : h0_b1;
        float a = b1[o];
        for (int k = 0; k < 64; ++k) a = fmaf(w1[o * 128 + k], task_emb[k], a);
        c01[tid] = a;
    }
}

// ---------------- K1: adp = softmax(relu(nv1@nv2), axis=1), padded to 2048 cols ----------------
__global__ __launch_bounds__(256) void adp_kernel(const float* __restrict__ nv1,
                                                  const float* __restrict__ nv2,
                                                  float* __restrict__ adp)
{
    __shared__ float nv1s[10];
    __shared__ float rbuf[4];
    int tid = threadIdx.x;
    int r = blockIdx.x;
    if (tid < 10) nv1s[tid] = nv1[r * 10 + tid];
    __syncthreads();

    float val[8];
    float vmax = -3.4e38f;
    #pragma unroll
    for (int s = 0; s < 8; ++s) {
        int j = tid + s * 256;
        if (j < NN) {
            float v = 0.f;
            #pragma unroll
            for (int k = 0; k < 10; ++k) v = fmaf(nv1s[k], nv2[k * NN + j], v);
            v = fmaxf(v, 0.f);
            val[s] = v;
            vmax = fmaxf(vmax, v);
        } else val[s] = -3.4e38f;
    }
    // block-reduce max
    for (int off = 32; off; off >>= 1) vmax = fmaxf(vmax, __shfl_down(vmax, off, 64));
    if ((tid & 63) == 0) rbuf[tid >> 6] = vmax;
    __syncthreads();
    vmax = fmaxf(fmaxf(rbuf[0], rbuf[1]), fmaxf(rbuf[2], rbuf[3]));
    __syncthreads();
    // exp + block-reduce sum
    float sum = 0.f;
    #pragma unroll
    for (int s = 0; s < 8; ++s) {
        int j = tid + s * 256;
        if (j < NN) { val[s] = expf(val[s] - vmax); sum += val[s]; }
    }
    for (int off = 32; off; off >>= 1) sum += __shfl_down(sum, off, 64);
    if ((tid & 63) == 0) rbuf[tid >> 6] = sum;
    __syncthreads();
    sum = rbuf[0] + rbuf[1] + rbuf[2] + rbuf[3];
    float inv = 1.f / sum;
    #pragma unroll
    for (int s = 0; s < 8; ++s) {
        int j = tid + s * 256;
        if (j < NN) adp[r * NPAD + j] = val[s] * inv;
    }
}

// ---------------- K2: fused temporal stack ----------------
// Block = 256 threads = 4 waves; each wave handles 8 items (lane = channel).
// LDS: xstate[32 items][64 ch][8 t]  (64KB)
//      flds/glds [c][k][o] (32KB each), slds [c][o] (16KB)  -> 144KB total
template<int LAYER, int D, int WIN, int WOUT, int P>
__device__ __forceinline__ void do_layer(
    float* __restrict__ xstate, float* __restrict__ flds, float* __restrict__ glds,
    float* __restrict__ slds,
    const float* __restrict__ filt_w, const float* __restrict__ filt_b,
    const float* __restrict__ gate_w, const float* __restrict__ gate_b,
    const float* __restrict__ skip_w, const float* __restrict__ skip_b,
    const float* __restrict__ bn_g, const float* __restrict__ bn_b,
    float* __restrict__ sacc)
{
    int tid = threadIdx.x;
    int wave = tid >> 6, o = tid & 63;
    // stage weights: global read coalesced, LDS write lane-transposed
    for (int idx = tid; idx < 8192; idx += 256) {
        int oo = idx >> 7, rem = idx & 127;
        int c = rem >> 1, k = rem & 1;
        flds[(c * 2 + k) * 64 + oo] = filt_w[LAYER * 8192 + idx];
        glds[(c * 2 + k) * 64 + oo] = gate_w[LAYER * 8192 + idx];
    }
    for (int idx = tid; idx < 4096; idx += 256) {
        int oo = idx >> 6, c = idx & 63;
        slds[c * 64 + oo] = skip_w[LAYER * 4096 + idx];
    }
    __syncthreads();

    float fb = filt_b[LAYER * 64 + o], gb = gate_b[LAYER * 64 + o];
    float skb = skip_b[LAYER * 64 + o];
    float bscale = bn_g[LAYER * 64 + o] * rsqrtf(1.0f + 1e-5f);
    float bshift = bn_b[LAYER * 64 + o];

    for (int gi = 0; gi < 8; ++gi) {
        int g = wave * 8 + gi;
        float* row = &xstate[(g * 64 + o) * 8];
        float xold[8];
        {
            float4 r0 = ((float4*)row)[0], r1 = ((float4*)row)[1];
            xold[0]=r0.x; xold[1]=r0.y; xold[2]=r0.z; xold[3]=r0.w;
            xold[4]=r1.x; xold[5]=r1.y; xold[6]=r1.z; xold[7]=r1.w;
        }
        float facc[WOUT], gacc[WOUT];
        #pragma unroll
        for (int t = 0; t < WOUT; ++t) { facc[t] = fb; gacc[t] = gb; }
        for (int c = 0; c < 64; ++c) {
            const float4* xr = (const float4*)&xstate[(g * 64 + c) * 8];
            float4 xa = xr[0], xb = xr[1];
            float xv[8] = {xa.x, xa.y, xa.z, xa.w, xb.x, xb.y, xb.z, xb.w};
            float wf0 = flds[c * 128 + o], wf1 = flds[c * 128 + 64 + o];
            float wg0 = glds[c * 128 + o], wg1 = glds[c * 128 + 64 + o];
            #pragma unroll
            for (int t = 0; t < WOUT; ++t) {
                facc[t] = fmaf(wf0, xv[t], facc[t]);
                facc[t] = fmaf(wf1, xv[t + D], facc[t]);
                gacc[t] = fmaf(wg0, xv[t], gacc[t]);
                gacc[t] = fmaf(wg1, xv[t + D], gacc[t]);
            }
        }
        float gated[WOUT];
        #pragma unroll
        for (int t = 0; t < WOUT; ++t)
            gated[t] = tanhf(facc[t]) * (1.0f / (1.0f + expf(-gacc[t])));
        // publish gated for skip conv (wave-lockstep; same-wave LDS ordering)
        #pragma unroll
        for (int t = 0; t < WOUT; ++t) row[t] = gated[t];
        float s = skb;
        for (int c = 0; c < 64; ++c)
            s = fmaf(slds[c * 64 + o], xstate[(g * 64 + c) * 8 + P], s);
        sacc[gi] += s;
        // residual + eval-mode BN, becomes next layer's input
        #pragma unroll
        for (int t = 0; t < WOUT; ++t)
            row[t] = fmaf(gated[t] + xold[t + D], bscale, bshift);
    }
    __syncthreads();
}

__global__ __launch_bounds__(256, 1) void temporal_kernel(
    const float* __restrict__ X,
    const float* __restrict__ start_w, const float* __restrict__ start_b,
    const float* __restrict__ filt_w, const float* __restrict__ filt_b,
    const float* __restrict__ gate_w, const float* __restrict__ gate_b,
    const float* __restrict__ skip_w, const float* __restrict__ skip_b,
    const float* __restrict__ bn_g, const float* __restrict__ bn_b,
    float* __restrict__ S)
{
    extern __shared__ float smem[];
    float* xstate = smem;           // 16384 floats
    float* flds   = smem + 16384;   // 8192
    float* glds   = smem + 24576;   // 8192
    float* slds   = smem + 32768;   // 4096
    float* xstage = flds;           // overlap: X staging (4096 floats) before weights

    int tid = threadIdx.x;
    int wave = tid >> 6, o = tid & 63;
    int item0 = blockIdx.x * 32;

    // stage X for 32 items: xstage[g][t*16+f]
    for (int idx = tid; idx < 32 * 128; idx += 256) {
        int g = idx >> 7, rem = idx & 127;
        int ig = item0 + g;
        int b = ig / NN, n = ig - b * NN;
        int t = rem >> 4, f = rem & 15;
        xstage[idx] = X[((b * TT + t) * NN + n) * NF + f];
    }
    __syncthreads();

    // start 1x1 conv (F=16 -> CH=64)
    {
        float wst[16];
        #pragma unroll
        for (int f4 = 0; f4 < 16; f4 += 4) {
            float4 v = *(const float4*)&start_w[o * 16 + f4];
            wst[f4] = v.x; wst[f4+1] = v.y; wst[f4+2] = v.z; wst[f4+3] = v.w;
        }
        float sb = start_b[o];
        for (int gi = 0; gi < 8; ++gi) {
            int g = wave * 8 + gi;
            float outv[8];
            #pragma unroll
            for (int t = 0; t < 8; ++t) {
                float acc = sb;
                const float* xr = &xstage[g * 128 + t * 16];
                #pragma unroll
                for (int f = 0; f < 16; ++f) acc = fmaf(wst[f], xr[f], acc);
                outv[t] = acc;
            }
            float4* wr = (float4*)&xstate[(g * 64 + o) * 8];
            wr[0] = make_float4(outv[0], outv[1], outv[2], outv[3]);
            wr[1] = make_float4(outv[4], outv[5], outv[6], outv[7]);
        }
    }
    __syncthreads();

    float sacc[8] = {0, 0, 0, 0, 0, 0, 0, 0};
    do_layer<0, 1, 8, 7, 6>(xstate, flds, glds, slds, filt_w, filt_b, gate_w, gate_b,
                            skip_w, skip_b, bn_g, bn_b, sacc);
    do_layer<1, 2, 7, 5, 4>(xstate, flds, glds, slds, filt_w, filt_b, gate_w, gate_b,
                            skip_w, skip_b, bn_g, bn_b, sacc);
    do_layer<2, 4, 5, 1, 0>(xstate, flds, glds, slds, filt_w, filt_b, gate_w, gate_b,
                            skip_w, skip_b, bn_g, bn_b, sacc);

    // write skip_final: S[n][b*64+o] (K-major for GEMM)
    for (int gi = 0; gi < 8; ++gi) {
        int ig = item0 + wave * 8 + gi;
        int b = ig / NN, n = ig - b * NN;
        S[n * BCD + b * 64 + o] = sacc[gi];
    }
}

// ---------------- K3: TN GEMM, C[m][n] = sum_k A[k][m]*B[k][n] ----------------
// A: 2048x2048 (adp), B: 2048x4096, C: 2048x4096. 128x128 tile, 8x8 micro.
__global__ __launch_bounds__(256) void gemm_tn(const float* __restrict__ A,
                                               const float* __restrict__ B,
                                               float* __restrict__ Cm)
{
    __shared__ float As[16][132];
    __shared__ float Bs[16][132];
    int tid = threadIdx.x;
    int tx = tid & 15, ty = tid >> 4;
    int m0 = blockIdx.y * 128, n0 = blockIdx.x * 128;
    float acc[8][8] = {};
    for (int k0 = 0; k0 < NPAD; k0 += 16) {
        #pragma unroll
        for (int l = 0; l < 2; ++l) {
            int fi = tid * 4 + l * 1024;
            int r = fi >> 7, c = fi & 127;
            *(float4*)&As[r][c] = *(const float4*)&A[(k0 + r) * NPAD + m0 + c];
            *(float4*)&Bs[r][c] = *(const float4*)&B[(k0 + r) * BCD + n0 + c];
        }
        __syncthreads();
        #pragma unroll
        for (int kk = 0; kk < 16; ++kk) {
            float a[8], b[8];
            *(float4*)&a[0] = *(float4*)&As[kk][ty * 8];
            *(float4*)&a[4] = *(float4*)&As[kk][ty * 8 + 4];
            *(float4*)&b[0] = *(float4*)&Bs[kk][tx * 8];
            *(float4*)&b[4] = *(float4*)&Bs[kk][tx * 8 + 4];
            #pragma unroll
            for (int i = 0; i < 8; ++i)
                #pragma unroll
                for (int j = 0; j < 8; ++j)
                    acc[i][j] = fmaf(a[i], b[j], acc[i][j]);
        }
        __syncthreads();
    }
    #pragma unroll
    for (int i = 0; i < 8; ++i) {
        int m = m0 + ty * 8 + i;
        *(float4*)&Cm[m * BCD + n0 + tx * 8]     = make_float4(acc[i][0], acc[i][1], acc[i][2], acc[i][3]);
        *(float4*)&Cm[m * BCD + n0 + tx * 8 + 4] = make_float4(acc[i][4], acc[i][5], acc[i][6], acc[i][7]);
    }
}

// ---------------- K4: gcn 1x1 + heads + outputs + partial reductions ----------------
__global__ __launch_bounds__(256) void head_kernel(
    const float* __restrict__ S, const float* __restrict__ x1, const float* __restrict__ x2,
    const float* __restrict__ wgcnT, const float* __restrict__ gcn_b,
    const float* __restrict__ c01, const float* __restrict__ w1tT,
    const float* __restrict__ h0_w2, const float* __restrict__ h0_b2,
    const float* __restrict__ h1_w2, const float* __restrict__ h1_b2,
    const int* __restrict__ Ct, const float* __restrict__ Yf,
    float* __restrict__ out, float* __restrict__ partials)
{
    __shared__ float hl[4][4][192];
    __shared__ float gxl[4][4][64];
    int tid = threadIdx.x;
    int wave = tid >> 6, o = tid & 63;
    int wid = blockIdx.x * 4 + wave;  // 0..2047
    float w2a = h0_w2[o], w2b = h1_w2[o];
    float b20 = h0_b2[0], b21 = h1_b2[0];
    float cb = gcn_b[o], c0a = c01[o], c0b = c01[64 + o];

    float accT = 0.f, accC = 0.f, bce = 0.f, cT = 0.f, cC = 0.f;

    for (int base = wid * 4; base < ITEMS; base += 2048 * 4) {
        // stage h = [skip, x1, x2] for 4 items
        #pragma unroll
        for (int it = 0; it < 4; ++it) {
            int item = base + it;
            int b = item / NN, n = item - b * NN;
            int off = n * BCD + b * 64 + o;
            hl[wave][it][o]       = S[off];
            hl[wave][it][64 + o]  = x1[off];
            hl[wave][it][128 + o] = x2[off];
        }
        // gcn 1x1 (192 -> 64) + relu
        float a0 = cb, a1 = cb, a2 = cb, a3 = cb;
        for (int j = 0; j < 192; ++j) {
            float w = wgcnT[j * 64 + o];
            a0 = fmaf(w, hl[wave][0][j], a0);
            a1 = fmaf(w, hl[wave][1][j], a1);
            a2 = fmaf(w, hl[wave][2][j], a2);
            a3 = fmaf(w, hl[wave][3][j], a3);
        }
        float gxv[4] = {fmaxf(a0, 0.f), fmaxf(a1, 0.f), fmaxf(a2, 0.f), fmaxf(a3, 0.f)};
        #pragma unroll
        for (int it = 0; it < 4; ++it) gxl[wave][it][o] = gxv[it];

        // heads: hh = relu(c0 + W1g·gx)
        float p0[4], p1[4];
        #pragma unroll
        for (int it = 0; it < 4; ++it) { p0[it] = c0a; p1[it] = c0b; }
        for (int c = 0; c < 64; ++c) {
            float w0 = w1tT[c * 64 + o];
            float w1 = w1tT[4096 + c * 64 + o];
            float g0 = gxl[wave][0][c], g1 = gxl[wave][1][c];
            float g2 = gxl[wave][2][c], g3 = gxl[wave][3][c];
            p0[0] = fmaf(w0, g0, p0[0]); p0[1] = fmaf(w0, g1, p0[1]);
            p0[2] = fmaf(w0, g2, p0[2]); p0[3] = fmaf(w0, g3, p0[3]);
            p1[0] = fmaf(w1, g0, p1[0]); p1[1] = fmaf(w1, g1, p1[1]);
            p1[2] = fmaf(w1, g2, p1[2]); p1[3] = fmaf(w1, g3, p1[3]);
        }
        #pragma unroll
        for (int it = 0; it < 4; ++it) {
            float r0 = w2a * fmaxf(p0[it], 0.f);
            float r1 = w2b * fmaxf(p1[it], 0.f);
            #pragma unroll
            for (int off = 32; off; off >>= 1) {
                r0 += __shfl_down(r0, off, 64);
                r1 += __shfl_down(r1, off, 64);
            }
            int item = base + it;
            int tt = Ct[item];
            if (o == 0) {
                float y0 = 1.f / (1.f + expf(-(r0 + b20)));
                float y1 = 1.f / (1.f + expf(-(r1 + b21)));
                float y = (tt > 0) ? y1 : y0;
                out[1 + item] = y;
                out[1 + ITEMS + item] = y0;
                out[1 + 2 * ITEMS + item] = y1;
                float yc = fminf(fmaxf(y, 1e-7f), 1.f - 1e-7f);
                float Yv = Yf[item];
                bce -= Yv * logf(yc) + (1.f - Yv) * logf(1.f - yc);
                if (tt > 0) cT += 1.f; else cC += 1.f;
            }
            if (tt > 0) accT += gxv[it]; else accC += gxv[it];
        }
    }
    // deterministic partials: [wid][0..63]=sumT, [64..127]=sumC, [128]=bce, [129]=cT, [130]=cC
    partials[wid * 132 + o] = accT;
    partials[wid * 132 + 64 + o] = accC;
    if (o == 0) {
        partials[wid * 132 + 128] = bce;
        partials[wid * 132 + 129] = cT;
        partials[wid * 132 + 130] = cC;
    }
}

// ---------------- K5: final loss ----------------
__global__ void finalize_kernel(const float* __restrict__ partials,
                                const float* __restrict__ task_emb,
                                float* __restrict__ out)
{
    __shared__ float red[131];
    int tid = threadIdx.x; // 128
    for (int slot = tid; slot < 131; slot += 128) {
        float s = 0.f;
        for (int w = 0; w < 2048; ++w) s += partials[w * 132 + slot];
        red[slot] = s;
    }
    __syncthreads();
    if (tid < 64) {
        float cT = red[129], cC = red[130];
        float iT = 1.f / fmaxf(cT, 1.f), iC = 1.f / fmaxf(cC, 1.f);
        float d1 = task_emb[tid] * (cT * iT) - task_emb[tid] * (cC * iC);
        float d2 = red[tid] * iT - red[64 + tid] * iC;
        float p = d1 * d1 + d2 * d2;
        #pragma unroll
        for (int off = 32; off; off >>= 1) p += __shfl_down(p, off, 64);
        if (tid == 0) out[0] = red[128] * (1.f / (float)ITEMS) + p;
    }
}

// ---------------- launch ----------------
extern "C" void kernel_launch(void* const* d_in, const int* in_sizes, int n_in,
                              void* d_out, int out_size, void* d_ws, size_t ws_size,
                              hipStream_t stream)
{
    const float* X       = (const float*)d_in[0];
    const int*   Ct      = (const int*)d_in[2];
    const float* Yf      = (const float*)d_in[3];
    const float* start_w = (const float*)d_in[5];
    const float* start_b = (const float*)d_in[6];
    const float* filt_w  = (const float*)d_in[7];
    const float* filt_b  = (const float*)d_in[8];
    const float* gate_w  = (const float*)d_in[9];
    const float* gate_b  = (const float*)d_in[10];
    const float* skip_w  = (const float*)d_in[11];
    const float* skip_b  = (const float*)d_in[12];
    const float* bn_g    = (const float*)d_in[13];
    const float* bn_b    = (const float*)d_in[14];
    const float* nv1     = (const float*)d_in[15];
    const float* nv2     = (const float*)d_in[16];
    const float* task    = (const float*)d_in[17];
    const float* gcn_w   = (const float*)d_in[18];
    const float* gcn_b   = (const float*)d_in[19];
    const float* h0_w1   = (const float*)d_in[20];
    const float* h0_b1   = (const float*)d_in[21];
    const float* h0_w2   = (const float*)d_in[22];
    const float* h0_b2   = (const float*)d_in[23];
    const float* h1_w1   = (const float*)d_in[24];
    const float* h1_b1   = (const float*)d_in[25];
    const float* h1_w2   = (const float*)d_in[26];
    const float* h1_b2   = (const float*)d_in[27];

    float* ws    = (float*)d_ws;
    float* adp   = ws + OFF_ADP;
    float* S     = ws + OFF_S;
    float* x1    = ws + OFF_X1;
    float* x2    = ws + OFF_X2;
    float* c01   = ws + OFF_C01;
    float* wgcnT = ws + OFF_WGCNT;
    float* w1tT  = ws + OFF_W1TT;
    float* part  = ws + OFF_PART;
    float* outp  = (float*)d_out;

    // zero only what padding requires: adp pad rows/cols (full zero is simplest)
    // and S pad rows (v >= 2000) so the padded-K GEMM contributes exactly 0.
    hipMemsetAsync(adp, 0, (size_t)NPAD * NPAD * sizeof(float), stream);
    hipMemsetAsync(S + (size_t)NN * BCD, 0, (size_t)(NPAD - NN) * BCD * sizeof(float), stream);

    prep_kernel<<<1, 256, 0, stream>>>(gcn_w, h0_w1, h0_b1, h1_w1, h1_b1, task,
                                       c01, wgcnT, w1tT);
    adp_kernel<<<NN, 256, 0, stream>>>(nv1, nv2, adp);

    const int K2_LDS = 36864 * 4; // 144 KiB dynamic LDS
    hipFuncSetAttribute(reinterpret_cast<const void*>(temporal_kernel),
                        hipFuncAttributeMaxDynamicSharedMemorySize, K2_LDS);
    temporal_kernel<<<ITEMS / 32, 256, K2_LDS, stream>>>(
        X, start_w, start_b, filt_w, filt_b, gate_w, gate_b,
        skip_w, skip_b, bn_g, bn_b, S);

    dim3 gg(BCD / 128, NPAD / 128);
    gemm_tn<<<gg, 256, 0, stream>>>(adp, S, x1);   // x1 = skip · adp
    gemm_tn<<<gg, 256, 0, stream>>>(adp, x1, x2);  // x2 = x1 · adp

    head_kernel<<<512, 256, 0, stream>>>(S, x1, x2, wgcnT, gcn_b, c01, w1tT,
                                         h0_w2, h0_b2, h1_w2, h1_b2,
                                         Ct, Yf, outp, part);
    finalize_kernel<<<1, 128, 0, stream>>>(part, task, outp);
}